// Round 1
// baseline (92.286 us; speedup 1.0000x reference)
//
#include <hip/hip_runtime.h>

// Problem constants (from reference):
//   left/right: [2, 32, 64, 128] f32, MAXDISP=192 -> D=48 coarse disparities
//   output: [2, 256, 512] f32 (soft-argmin disparity map)
#define BB 2
#define CC 32
#define HC 64
#define WC 128
#define DC 48
#define HO 256
#define WO 512
#define MAXD 192

// Kernel 1: sum over channel axis -> L[b,h,w], R[b,h,w]  (2*64*128 each)
__global__ __launch_bounds__(256) void sum_channels_kernel(
    const float* __restrict__ left, const float* __restrict__ right,
    float* __restrict__ Lsum, float* __restrict__ Rsum) {
    int idx = blockIdx.x * blockDim.x + threadIdx.x;  // [0, BB*HC*WC)
    int b  = idx >> 13;          // HC*WC = 8192
    int hw = idx & 8191;
    const float* lp = left  + (size_t)b * CC * (HC * WC) + hw;
    const float* rp = right + (size_t)b * CC * (HC * WC) + hw;
    float ls = 0.f, rs = 0.f;
#pragma unroll
    for (int c = 0; c < CC; ++c) {
        ls += lp[c * (HC * WC)];
        rs += rp[c * (HC * WC)];
    }
    Lsum[idx] = ls;
    Rsum[idx] = rs;
}

// Kernel 2: per output pixel -> 48 coarse vol values (bilinear HW interp of the
// collapsed cost volume), then fused d-upsample + softmax + expectation.
__global__ __launch_bounds__(256) void disparity_kernel(
    const float* __restrict__ Lsum, const float* __restrict__ Rsum,
    float* __restrict__ out) {
    int idx = blockIdx.x * blockDim.x + threadIdx.x;  // [0, BB*HO*WO)
    int ww = idx & (WO - 1);
    int hh = (idx >> 9) & (HO - 1);
    int b  = idx >> 17;

    // align_corners=True source coords
    float src_h = (float)hh * (63.0f / 255.0f);
    int h0 = (int)src_h; if (h0 > HC - 1) h0 = HC - 1;
    int h1 = min(h0 + 1, HC - 1);
    float fh = src_h - (float)h0;

    float src_w = (float)ww * (127.0f / 511.0f);
    int w0 = (int)src_w; if (w0 > WC - 1) w0 = WC - 1;
    int w1 = min(w0 + 1, WC - 1);
    float fw = src_w - (float)w0;

    const float* Lb = Lsum + b * (HC * WC);
    const float* Rb = Rsum + b * (HC * WC);
    const float* L0 = Lb + h0 * WC;
    const float* L1 = Lb + h1 * WC;
    const float* R0 = Rb + h0 * WC;
    const float* R1 = Rb + h1 * WC;

    float A00 = (1.f - fh) * (1.f - fw);
    float A01 = (1.f - fh) * fw;
    float A10 = fh * (1.f - fw);
    float A11 = fh * fw;

    // d-independent left contributions per w-column (mask is per (w,d))
    float LA = A00 * L0[w0] + A10 * L1[w0];
    float LB = A01 * L0[w1] + A11 * L1[w1];

    const float scale = 1.0f / 64.0f;  // mean over 2C = 64 channels

    // coarse disparity profile v[d] (kept in registers via full unroll)
    float v[DC];
    float m = -1e30f;
#pragma unroll
    for (int d = 0; d < DC; ++d) {
        int i0 = w0 - d; float m0 = (i0 >= 0) ? 1.f : 0.f; i0 = max(i0, 0);
        int i1 = w1 - d; float m1 = (i1 >= 0) ? 1.f : 0.f; i1 = max(i1, 0);
        float val = m0 * (LA + A00 * R0[i0] + A10 * R1[i0])
                  + m1 * (LB + A01 * R0[i1] + A11 * R1[i1]);
        val *= scale;
        v[d] = val;
        m = fmaxf(m, val);
    }
    // every upsampled x[dd] is a convex combo of adjacent v[d] => m >= max x

    // fused: 48->192 linear upsample + softmax + soft-argmin expectation
    float lsum = 0.f, ssum = 0.f;
#pragma unroll
    for (int d = 0; d < DC; ++d) {
        // dd range with floor(dd*47/191) == d (exact integer partition; the
        // float product below never crosses an integer inside this range)
        int lo = (d * (MAXD - 1) + (DC - 2)) / (DC - 1);          // ceil(d*191/47)
        int hi = ((d + 1) * (MAXD - 1) + (DC - 2)) / (DC - 1) - 1;
        if (hi > MAXD - 1) hi = MAXD - 1;
        float vcur  = v[d];
        float vnext = (d < DC - 1) ? v[d + 1] : v[d];
#pragma unroll
        for (int dd = lo; dd <= hi; ++dd) {
            float src = (float)dd * (47.0f / 191.0f);
            float wd  = src - (float)d;
            float x   = vcur + wd * (vnext - vcur);
            float e   = __expf(x - m);
            lsum += e;
            ssum += e * (float)dd;
        }
    }
    out[idx] = ssum / lsum;
}

extern "C" void kernel_launch(void* const* d_in, const int* in_sizes, int n_in,
                              void* d_out, int out_size, void* d_ws, size_t ws_size,
                              hipStream_t stream) {
    const float* left  = (const float*)d_in[0];
    const float* right = (const float*)d_in[1];
    float* out  = (float*)d_out;
    float* Lsum = (float*)d_ws;                       // BB*HC*WC floats
    float* Rsum = Lsum + BB * HC * WC;                // BB*HC*WC floats

    int n1 = BB * HC * WC;                            // 16384
    sum_channels_kernel<<<n1 / 256, 256, 0, stream>>>(left, right, Lsum, Rsum);

    int n2 = BB * HO * WO;                            // 262144
    disparity_kernel<<<n2 / 256, 256, 0, stream>>>(Lsum, Rsum, out);
}

// Round 2
// 74.058 us; speedup vs baseline: 1.2461x; 1.2461x over previous
//
#include <hip/hip_runtime.h>

// Problem constants (from reference):
//   left/right: [2, 32, 64, 128] f32, MAXDISP=192 -> D=48 coarse disparities
//   output: [2, 256, 512] f32 (soft-argmin disparity map)
#define BB 2
#define CC 32
#define HC 64
#define WC 128
#define DC 48
#define HO 256
#define WO 512
#define MAXD 192

// One block per output row (b, hh): 512 rows total, 512 threads (one per ww).
// Phase 1: each thread computes one 32-channel sum for (matrix in {L,R}, row in
//          {h0,h1}, w) -> LDS (coalesced global loads).
// Phase 2: blend rows with fh (constant per block) -> Lh[128], Rh[128] in LDS.
// Phase 3: per-pixel d-loop reads only LDS; fused d-upsample+softmax+argmin.
__global__ __launch_bounds__(512) void fused_disparity_kernel(
    const float* __restrict__ left, const float* __restrict__ right,
    float* __restrict__ out) {
    __shared__ float sbuf[4][WC];   // 0:L@h0 1:L@h1 2:R@h0 3:R@h1 (channel sums)
    __shared__ float Lh[WC];
    __shared__ float Rh[WC];

    int r  = blockIdx.x;            // [0, BB*HO)
    int b  = r >> 8;
    int hh = r & (HO - 1);

    // align_corners=True vertical source coords (fh constant per block)
    float src_h = (float)hh * (63.0f / 255.0f);
    int h0 = (int)src_h; if (h0 > HC - 1) h0 = HC - 1;
    int h1 = min(h0 + 1, HC - 1);
    float fh = src_h - (float)h0;

    int t   = threadIdx.x;
    int w   = t & (WC - 1);
    int sel = t >> 7;               // 0..3

    // Phase 1: channel sums (coalesced: consecutive threads -> consecutive w)
    {
        const float* basep = (sel < 2) ? left : right;
        int hrow = (sel & 1) ? h1 : h0;
        const float* p = basep + (size_t)b * (CC * HC * WC) + hrow * WC + w;
        float s = 0.f;
#pragma unroll
        for (int c = 0; c < CC; ++c) s += p[c * (HC * WC)];
        sbuf[sel][w] = s;
    }
    __syncthreads();

    // Phase 2: fh-blend into Lh / Rh
    if (t < WC) {
        Lh[t] = (1.f - fh) * sbuf[0][t] + fh * sbuf[1][t];
    } else if (t < 2 * WC) {
        int u = t - WC;
        Rh[u] = (1.f - fh) * sbuf[2][u] + fh * sbuf[3][u];
    }
    __syncthreads();

    // Phase 3: per-pixel work (all gathers hit LDS)
    int ww = t;
    float src_w = (float)ww * (127.0f / 511.0f);
    int w0 = (int)src_w; if (w0 > WC - 1) w0 = WC - 1;
    int w1 = min(w0 + 1, WC - 1);
    float fw = src_w - (float)w0;

    const float scale = 1.0f / 64.0f;   // mean over 2C = 64 channels
    float c0 = (1.f - fw) * scale;
    float c1 = fw * scale;
    float lw0 = Lh[w0];
    float lw1 = Lh[w1];

    float v[DC];
    float m = -1e30f;
#pragma unroll
    for (int d = 0; d < DC; ++d) {
        int i0 = w0 - d; float m0 = (i0 >= 0) ? 1.f : 0.f; i0 = max(i0, 0);
        int i1 = w1 - d; float m1 = (i1 >= 0) ? 1.f : 0.f; i1 = max(i1, 0);
        float val = m0 * c0 * (lw0 + Rh[i0]) + m1 * c1 * (lw1 + Rh[i1]);
        v[d] = val;
        m = fmaxf(m, val);
    }
    // every upsampled x[dd] is a convex combo of adjacent v[d] => m >= max x

    // fused: 48->192 linear upsample + softmax + soft-argmin expectation
    float lsum = 0.f, ssum = 0.f;
#pragma unroll
    for (int d = 0; d < DC; ++d) {
        int lo = (d * (MAXD - 1) + (DC - 2)) / (DC - 1);          // ceil(d*191/47)
        int hi = ((d + 1) * (MAXD - 1) + (DC - 2)) / (DC - 1) - 1;
        if (hi > MAXD - 1) hi = MAXD - 1;
        float vcur  = v[d];
        float vnext = (d < DC - 1) ? v[d + 1] : v[d];
#pragma unroll
        for (int dd = lo; dd <= hi; ++dd) {
            float src = (float)dd * (47.0f / 191.0f);
            float wd  = src - (float)d;
            float x   = vcur + wd * (vnext - vcur);
            float e   = __expf(x - m);
            lsum += e;
            ssum += e * (float)dd;
        }
    }
    out[r * WO + ww] = ssum / lsum;
}

extern "C" void kernel_launch(void* const* d_in, const int* in_sizes, int n_in,
                              void* d_out, int out_size, void* d_ws, size_t ws_size,
                              hipStream_t stream) {
    const float* left  = (const float*)d_in[0];
    const float* right = (const float*)d_in[1];
    float* out = (float*)d_out;

    fused_disparity_kernel<<<BB * HO, WO, 0, stream>>>(left, right, out);
}

// Round 3
// 70.739 us; speedup vs baseline: 1.3046x; 1.0469x over previous
//
#include <hip/hip_runtime.h>

// Problem constants (from reference):
//   left/right: [2, 32, 64, 128] f32, MAXDISP=192 -> D=48 coarse disparities
//   output: [2, 256, 512] f32 (soft-argmin disparity map)
#define BB 2
#define CC 32
#define HC 64
#define WC 128
#define DC 48
#define HO 256
#define WO 512
#define MAXD 192

// ---------------------------------------------------------------------------
// Kernel A: channel sums -> Ls[b][h][w], Rs[b][h][w]  (each 2*64*128 f32)
// grid 256 blocks x 256 threads; block -> (mat, b, h); threads: sel=t>>7 sums
// 16 channels (coalesced over w), LDS-combine the two halves.
// ---------------------------------------------------------------------------
__global__ __launch_bounds__(256) void sum_channels_kernel(
    const float* __restrict__ left, const float* __restrict__ right,
    float* __restrict__ Ls, float* __restrict__ Rs) {
    __shared__ float sbuf[2][WC];
    int blk = blockIdx.x;            // [0,256)
    int m   = blk >> 7;              // 0 = left, 1 = right
    int b   = (blk >> 6) & 1;
    int h   = blk & (HC - 1);
    int t   = threadIdx.x;
    int sel = t >> 7;                // channel half
    int w   = t & (WC - 1);

    const float* src = (m ? right : left)
                     + (size_t)b * (CC * HC * WC)
                     + (size_t)(sel * 16) * (HC * WC) + h * WC + w;
    float s = 0.f;
#pragma unroll
    for (int c = 0; c < 16; ++c) s += src[c * (HC * WC)];
    sbuf[sel][w] = s;
    __syncthreads();
    if (t < WC) {
        float* dst = m ? Rs : Ls;
        dst[b * (HC * WC) + h * WC + t] = sbuf[0][t] + sbuf[1][t];
    }
}

// ---------------------------------------------------------------------------
// Kernel B: per output pixel, fused bilinear + cost-volume collapse +
// d-upsample + softmax + soft-argmin. dd range split 4-ways across waves.
// ---------------------------------------------------------------------------
template <int K>
__device__ inline void quarter_work(const float* __restrict__ Rh,
                                    int w0, int w1, float c0, float c1,
                                    float lw0, float lw1,
                                    float& plsum, float& pssum) {
    constexpr int DDLO = 48 * K;
    constexpr int DDHI = 48 * K + 47;
    constexpr int DLO  = (DDLO * (DC - 1)) / (MAXD - 1);   // floor
    constexpr int DHI  = (DDHI * (DC - 1)) / (MAXD - 1);
    constexpr int NV   = DHI - DLO + 2;                    // v[DLO .. DHI+1]

    float vv[NV];
#pragma unroll
    for (int j = 0; j < NV; ++j) {
        int d = DLO + j;
        if (d > DC - 1) { vv[j] = vv[j - 1]; continue; }   // clamp v[48]->v[47]
        int i0 = w0 - d; float m0 = (i0 >= 0) ? 1.f : 0.f; i0 = max(i0, 0);
        int i1 = w1 - d; float m1 = (i1 >= 0) ? 1.f : 0.f; i1 = max(i1, 0);
        vv[j] = m0 * c0 * (lw0 + Rh[i0]) + m1 * c1 * (lw1 + Rh[i1]);
    }
    float ls = 0.f, ss = 0.f;
#pragma unroll
    for (int dd = DDLO; dd <= DDHI; ++dd) {
        int d    = (dd * (DC - 1)) / (MAXD - 1);           // compile-time fold
        float wd = (float)dd * (47.0f / 191.0f) - (float)d;
        float vc = vv[d - DLO];
        float x  = vc + wd * (vv[d - DLO + 1] - vc);
        float e  = __expf(x);                              // |x| < ~1: no max needed
        ls += e;
        ss += e * (float)dd;
    }
    plsum = ls;
    pssum = ss;
}

__global__ __launch_bounds__(512) void disparity_kernel(
    const float* __restrict__ Ls, const float* __restrict__ Rs,
    float* __restrict__ out) {
    __shared__ float Lh[WC];
    __shared__ float Rh[WC];
    __shared__ float redL[4][WC];
    __shared__ float redS[4][WC];

    int blk = blockIdx.x;            // [0, 2048)
    int r   = blk >> 2;              // output row [0, BB*HO)
    int g   = blk & 3;               // column group
    int b   = r >> 8;
    int hh  = r & (HO - 1);

    float src_h = (float)hh * (63.0f / 255.0f);
    int h0 = (int)src_h; if (h0 > HC - 1) h0 = HC - 1;
    int h1 = min(h0 + 1, HC - 1);
    float fh = src_h - (float)h0;

    int t = threadIdx.x;

    // Phase 1: load + fh-blend the two coarse rows (L2-resident, coalesced)
    if (t < WC) {
        const float* p = Ls + b * (HC * WC) + t;
        Lh[t] = (1.f - fh) * p[h0 * WC] + fh * p[h1 * WC];
    } else if (t < 2 * WC) {
        int u = t - WC;
        const float* p = Rs + b * (HC * WC) + u;
        Rh[u] = (1.f - fh) * p[h0 * WC] + fh * p[h1 * WC];
    }
    __syncthreads();

    // Phase 2: per-pixel quarter work. k = t>>7 is wave-uniform (waves 2k,2k+1).
    int p = t & (WC - 1);            // pixel within group
    int k = t >> 7;                  // dd quarter
    int ww = g * WC + p;

    float src_w = (float)ww * (127.0f / 511.0f);
    int w0 = (int)src_w; if (w0 > WC - 1) w0 = WC - 1;
    int w1 = min(w0 + 1, WC - 1);
    float fw = src_w - (float)w0;

    const float scale = 1.0f / 64.0f;    // mean over 2C = 64 channels
    float c0 = (1.f - fw) * scale;
    float c1 = fw * scale;
    float lw0 = Lh[w0];
    float lw1 = Lh[w1];

    float pls, pss;
    switch (k) {                      // wave-uniform branch, no divergence
        case 0: quarter_work<0>(Rh, w0, w1, c0, c1, lw0, lw1, pls, pss); break;
        case 1: quarter_work<1>(Rh, w0, w1, c0, c1, lw0, lw1, pls, pss); break;
        case 2: quarter_work<2>(Rh, w0, w1, c0, c1, lw0, lw1, pls, pss); break;
        default: quarter_work<3>(Rh, w0, w1, c0, c1, lw0, lw1, pls, pss); break;
    }
    redL[k][p] = pls;
    redS[k][p] = pss;
    __syncthreads();

    // Phase 3: combine quarters, soft-argmin, coalesced store
    if (t < WC) {
        float ls = redL[0][t] + redL[1][t] + redL[2][t] + redL[3][t];
        float ss = redS[0][t] + redS[1][t] + redS[2][t] + redS[3][t];
        out[r * WO + g * WC + t] = ss / ls;
    }
}

extern "C" void kernel_launch(void* const* d_in, const int* in_sizes, int n_in,
                              void* d_out, int out_size, void* d_ws, size_t ws_size,
                              hipStream_t stream) {
    const float* left  = (const float*)d_in[0];
    const float* right = (const float*)d_in[1];
    float* out = (float*)d_out;
    float* Ls  = (float*)d_ws;                 // BB*HC*WC floats
    float* Rs  = Ls + BB * HC * WC;            // BB*HC*WC floats

    sum_channels_kernel<<<256, 256, 0, stream>>>(left, right, Ls, Rs);
    disparity_kernel<<<BB * HO * 4, 512, 0, stream>>>(Ls, Rs, out);
}